// Round 11
// baseline (117.954 us; speedup 1.0000x reference)
//
#include <hip/hip_runtime.h>

#define BSZ  8192
#define DDIM 256
#define BM 128
#define BN 128
#define NT   64                  // tiles per dimension
#define NTRI (NT * (NT + 1) / 2) // 2080 upper-triangle tiles

typedef float f32x4 __attribute__((ext_vector_type(4)));
typedef short bf16x8 __attribute__((ext_vector_type(8)));

__device__ __forceinline__ unsigned short f32_to_bf16(float f) {
    unsigned int u = __float_as_uint(f);
    u += 0x7fffu + ((u >> 16) & 1u);   // RNE
    return (unsigned short)(u >> 16);
}

#if __has_builtin(__builtin_amdgcn_exp2f)
__device__ __forceinline__ float fast_exp2(float x) { return __builtin_amdgcn_exp2f(x); }
#else
__device__ __forceinline__ float fast_exp2(float x) {
    float r;
    asm("v_exp_f32 %0, %1" : "=v"(r) : "v"(x));
    return r;
}
#endif

// epilogue constants
#define K_E1   20.60992915555662f    // (1/T)*log2(e)
#define K_E2  -20.60992915555662f
#define K_INVT 14.285714285714286f   // 1/T
#define K_N1   1.4285714285714286f   // 1/(1-0.3)
#define K_N2   0.5714285714285714f   // 0.4/0.7

// ---------------- DPP 16-lane sum (VALU pipe, not DS pipe) ----------------
template<int CTRL>
__device__ __forceinline__ float dpp_add(float v) {
    int t = __builtin_amdgcn_update_dpp(0, __float_as_int(v), CTRL, 0xF, 0xF, true);
    return v + __int_as_float(t);
}
__device__ __forceinline__ float red16(float v) {
    v = dpp_add<0xB1>(v);    // quad_perm [1,0,3,2]  (^1)
    v = dpp_add<0x4E>(v);    // quad_perm [2,3,0,1]  (^2)
    v = dpp_add<0x141>(v);   // row_half_mirror
    v = dpp_add<0x140>(v);   // row_mirror
    return v;
}

// ---------------- LDS bank swizzle for norm staging (bijective) ----------------
__device__ __forceinline__ int swz(int b) {
    return b ^ ((((b >> 7) ^ (b >> 10)) & 7) << 4);
}

// ---------------- triangular tile decode (supertile-swizzled, 64x64) ----------------
__device__ __forceinline__ void decode_tile(int t, int& It, int& Jt) {
    const int off1 = 136, off2 = 392, off3 = 648, off4 = 904, off5 = 1040,
              off6 = 1296, off7 = 1552, off8 = 1688, off9 = 1944;
    int b = (t >= off1) + (t >= off2) + (t >= off3) + (t >= off4) + (t >= off5)
          + (t >= off6) + (t >= off7) + (t >= off8) + (t >= off9);
    int si, sj, r0;
    switch (b) {
        case 0: si = 0; sj = 0; r0 = 0;    break;
        case 1: si = 0; sj = 1; r0 = off1; break;
        case 2: si = 0; sj = 2; r0 = off2; break;
        case 3: si = 0; sj = 3; r0 = off3; break;
        case 4: si = 1; sj = 1; r0 = off4; break;
        case 5: si = 1; sj = 2; r0 = off5; break;
        case 6: si = 1; sj = 3; r0 = off6; break;
        case 7: si = 2; sj = 2; r0 = off7; break;
        case 8: si = 2; sj = 3; r0 = off8; break;
        default: si = 3; sj = 3; r0 = off9; break;
    }
    const int rr = t - r0;
    int il, jl;
    if (si == sj) {
        il = 0;
        #pragma unroll
        for (int q = 1; q < 16; q++) if (rr >= (16 * q - (q * (q - 1)) / 2)) il = q;
        jl = il + (rr - (16 * il - (il * (il - 1)) / 2));
    } else {
        il = rr >> 4;
        jl = rr & 15;
    }
    It = si * 16 + il;
    Jt = sj * 16 + jl;
}

// ---------------- L2-normalize rows; MFMA-native output; zero posAcc+counter ----------------
__global__ __launch_bounds__(256) void norm_kernel(const float* __restrict__ feat,
                                                   unsigned short* __restrict__ anchorT,
                                                   float* __restrict__ posAcc,
                                                   unsigned int* __restrict__ counter) {
    __shared__ __align__(16) unsigned short img[8 * 512];    // 8 KB: 8 x 1KB tiles
    char* const imgb = (char*)img;
    const int tid  = threadIdx.x;
    const int wid  = tid >> 6;
    const int lane = tid & 63;
    const int R    = blockIdx.x;          // 16-row tile
    const int R0   = R * 16;

    if (tid < 64) posAcc[blockIdx.x * 64 + tid] = 0.0f;       // 512*64 = 32768 = BSZ*4
    if (blockIdx.x == 0 && tid == 0) *counter = 0u;

    #pragma unroll
    for (int it = 0; it < 4; it++) {
        const int row = R0 + it * 4 + wid;
        const float4 v = ((const float4*)(feat + (size_t)row * DDIM))[lane];
        float ss = v.x * v.x + v.y * v.y + v.z * v.z + v.w * v.w;
        #pragma unroll
        for (int off = 32; off > 0; off >>= 1) ss += __shfl_xor(ss, off, 64);
        const float inv = rsqrtf(ss);
        ushort4 o;
        o.x = f32_to_bf16(v.x * inv);
        o.y = f32_to_bf16(v.y * inv);
        o.z = f32_to_bf16(v.z * inv);
        o.w = f32_to_bf16(v.w * inv);
        const int C    = lane >> 3;                           // k/32 (k = lane*4)
        const int l16  = (row & 15) + (((lane >> 1) & 3) << 4);
        const int wb   = (C << 10) + (l16 << 4) + ((lane & 1) << 3);
        *(ushort4*)(imgb + swz(wb)) = o;
    }
    __syncthreads();
    #pragma unroll
    for (int p = 0; p < 2; p++) {
        const int c = p * 4 + wid;                            // chunk 0..7 (= C)
        *(bf16x8*)(anchorT + ((size_t)(c * 512 + R)) * 512 + lane * 8) =
            *(const bf16x8*)(imgb + swz((c << 10) + (lane << 4)));
    }
}

// ---------------- async global -> LDS, 16B/lane ----------------
__device__ __forceinline__ void gload_lds16(const unsigned short* g, unsigned short* l) {
    __builtin_amdgcn_global_load_lds(
        (const __attribute__((address_space(1))) void*)g,
        (__attribute__((address_space(3))) void*)l, 16, 0, 0);
}

// ---------------- fused 128x128 sim-tile + loss partials (upper triangle) ----------------
// 256 threads / 4 waves; wave = 32x128 sub-tile (2 A-frag x 8 B-frag, acc[2][8]).
// QUAD-buffered LDS (4 x 8 KB A + 4 x 8 KB B = 64 KB), PREFETCH DEPTH 2: at
// iteration c stage chunk c+2 into buf[(c+2)&3]. Safety: that buffer's last
// readers were iteration c-2, whose ds_reads retired before BAR(c-1), which the
// staging wave has passed. (3 buffers cannot do depth-2: (c+2)%3==(c-1)%3 races
// with iteration c-1 readers.) Counted vmcnt(8) = two newer 4-load stages in
// flight; chunk c has ~2 compute iterations (~700 cyc) to cover L2 latency.
// ONE barrier per chunk, no lgkmcnt drain. s_setprio(1) wraps the MFMA cluster.
// Ledger: 256^2 tile spills (R5/R6); tight reg caps spill (R3); A-bypass-LDS
// regresses (R9); depth-1/3-buf (R8) = 108.4us total, the baseline to beat.
__global__ __launch_bounds__(256, 3) void simloss_kernel(
    const unsigned short* __restrict__ anchorT,
    const int* __restrict__ labels,
    float* __restrict__ part,          // float2 [NT][BSZ]
    float* __restrict__ posAcc)        // [BSZ][4] {s1, w1, s2corr, cnt}
{
    __shared__ __align__(16) unsigned short Abuf[4][4096];   // 4 x 8 KB
    __shared__ __align__(16) unsigned short Bbuf[4][4096];   // 4 x 8 KB
    float* const colDT = (float*)Abuf;   // [4][128][2] = 4 KB alias (epilogue only)

    int It, Jt;
    decode_tile(blockIdx.x, It, Jt);
    const bool diag = (It == Jt);
    const int I0 = It * BM, J0 = Jt * BN;

    const int tid  = threadIdx.x;
    const int lane = tid & 63;
    const int w    = tid >> 6;       // 0..3 ; wave rows w*32..+31
    const int cl   = lane & 15;
    const int rg   = lane >> 4;
    const int laneOff = lane * 8;    // shorts (16 B)

    f32x4 acc[2][8];
    #pragma unroll
    for (int f = 0; f < 2; f++)
        #pragma unroll
        for (int g = 0; g < 8; g++)
            acc[f][g] = (f32x4){0.f, 0.f, 0.f, 0.f};

    // chunk c = 32-wide K slice; anchorT granule layout [c][512 rowtiles][512]
    const unsigned short* aSrc = anchorT + (size_t)It * 4096;
    const unsigned short* bSrc = anchorT + (size_t)Jt * 4096;

    // 4 gloads/thread/chunk: each wave stages 2 of the 8 granules per matrix
    #define STAGE(c, b)                                                                 \
        do {                                                                            \
            const size_t off = (size_t)(c) * 262144;                                    \
            gload_lds16(aSrc + off + tid * 8,        &Abuf[b][w * 512]);                \
            gload_lds16(aSrc + off + 2048 + tid * 8, &Abuf[b][2048 + w * 512]);         \
            gload_lds16(bSrc + off + tid * 8,        &Bbuf[b][w * 512]);                \
            gload_lds16(bSrc + off + 2048 + tid * 8, &Bbuf[b][2048 + w * 512]);         \
        } while (0)

    // prologue: chunks 0 and 1 in flight (8 DMA ops)
    STAGE(0, 0);
    STAGE(1, 1);

    #pragma unroll
    for (int c = 0; c < 8; c++) {
        if (c < 6) {
            STAGE(c + 2, (c + 2) & 3);
            // outstanding: chunk c (4), c+1 (4), c+2 (4); drain chunk c only
            asm volatile("s_waitcnt vmcnt(8)" ::: "memory");
        } else if (c == 6) {
            asm volatile("s_waitcnt vmcnt(4)" ::: "memory");   // drain chunk 6; 7 in flight
        } else {
            asm volatile("s_waitcnt vmcnt(0)" ::: "memory");
        }
        __builtin_amdgcn_s_barrier();
        __builtin_amdgcn_sched_barrier(0);   // keep ds_reads below the barrier

        const int bc = c & 3;
        const unsigned short* aB = &Abuf[bc][(w * 2) * 512 + laneOff];
        const unsigned short* bB = &Bbuf[bc][laneOff];
        const bf16x8 a0 = *(const bf16x8*)(aB);
        const bf16x8 a1 = *(const bf16x8*)(aB + 512);
        __builtin_amdgcn_s_setprio(1);
        #pragma unroll
        for (int gh = 0; gh < 2; gh++) {
            const bf16x8 b0 = *(const bf16x8*)(bB + (gh * 4 + 0) * 512);
            const bf16x8 b1 = *(const bf16x8*)(bB + (gh * 4 + 1) * 512);
            const bf16x8 b2 = *(const bf16x8*)(bB + (gh * 4 + 2) * 512);
            const bf16x8 b3 = *(const bf16x8*)(bB + (gh * 4 + 3) * 512);
            acc[0][gh*4+0] = __builtin_amdgcn_mfma_f32_16x16x32_bf16(a0, b0, acc[0][gh*4+0], 0, 0, 0);
            acc[1][gh*4+0] = __builtin_amdgcn_mfma_f32_16x16x32_bf16(a1, b0, acc[1][gh*4+0], 0, 0, 0);
            acc[0][gh*4+1] = __builtin_amdgcn_mfma_f32_16x16x32_bf16(a0, b1, acc[0][gh*4+1], 0, 0, 0);
            acc[1][gh*4+1] = __builtin_amdgcn_mfma_f32_16x16x32_bf16(a1, b1, acc[1][gh*4+1], 0, 0, 0);
            acc[0][gh*4+2] = __builtin_amdgcn_mfma_f32_16x16x32_bf16(a0, b2, acc[0][gh*4+2], 0, 0, 0);
            acc[1][gh*4+2] = __builtin_amdgcn_mfma_f32_16x16x32_bf16(a1, b2, acc[1][gh*4+2], 0, 0, 0);
            acc[0][gh*4+3] = __builtin_amdgcn_mfma_f32_16x16x32_bf16(a0, b3, acc[0][gh*4+3], 0, 0, 0);
            acc[1][gh*4+3] = __builtin_amdgcn_mfma_f32_16x16x32_bf16(a1, b3, acc[1][gh*4+3], 0, 0, 0);
        }
        __builtin_amdgcn_s_setprio(0);
        // no trailing barrier: buf[c&3] is not rewritten until iteration c+2,
        // and all reads of it retired before BAR(c+1).
    }
    #undef STAGE

    // ---- epilogue: single pass; rows stored direct; labels from global (L2-hot) ----
    int lj[8];
    #pragma unroll
    for (int g = 0; g < 8; g++) lj[g] = labels[J0 + g * 16 + cl];

    float cd[8] = {0.f,0.f,0.f,0.f,0.f,0.f,0.f,0.f};
    float ct[8] = {0.f,0.f,0.f,0.f,0.f,0.f,0.f,0.f};
    float2* const part2 = (float2*)part;

    #pragma unroll
    for (int f = 0; f < 2; f++) {
        float rd[4] = {0.f, 0.f, 0.f, 0.f}, rt[4] = {0.f, 0.f, 0.f, 0.f};
        const int rbase = I0 + w * 32 + f * 16 + rg * 4;
        const int4 lv = *(const int4*)(labels + rbase);
        const int li[4] = {lv.x, lv.y, lv.z, lv.w};
        #pragma unroll
        for (int g = 0; g < 8; g++) {
            const int lj_ = lj[g];
            const bool granule = (w * 2 + f) == g;   // 16x16 block on tile diagonal
            const f32x4 c4 = acc[f][g];
            #pragma unroll
            for (int r = 0; r < 4; r++) {
                const float s = c4[r];
                const bool self = diag && granule && ((rg * 4 + r) == cl);
                const float e  = self ? 0.f : fast_exp2(fmaf(s, K_E1, K_E2));
                const float wn = fmaxf(fmaf(s, K_N1, K_N2), 1.0f);
                const float we = wn * e;
                rd[r] += e;  rt[r] += we;
                if (!diag) { cd[g] += e; ct[g] += we; }
                if (li[r] == lj_ && !self) {   // rare (~0.1%)
                    const float wp = fmaxf(1.5f - s, 1.0f);
                    const float slp = fmaf(s, K_INVT, -K_INVT) * wp;
                    float* pi = posAcc + (size_t)(rbase + r) * 4;
                    atomicAdd(pi + 0, slp);
                    atomicAdd(pi + 1, wp);
                    atomicAdd(pi + 2, we);
                    atomicAdd(pi + 3, 1.0f);
                    if (!diag) {
                        float* pj = posAcc + (size_t)(J0 + g * 16 + cl) * 4;
                        atomicAdd(pj + 0, slp);
                        atomicAdd(pj + 1, wp);
                        atomicAdd(pj + 2, we);
                        atomicAdd(pj + 3, 1.0f);
                    }
                }
            }
        }
        #pragma unroll
        for (int r = 0; r < 4; r++) {
            rd[r] = red16(rd[r]);
            rt[r] = red16(rt[r]);
        }
        if (cl == 0) {
            #pragma unroll
            for (int r = 0; r < 4; r++) {
                float2 v; v.x = rd[r]; v.y = rt[r];
                part2[(size_t)Jt * BSZ + rbase + r] = v;   // rows are wave-local
            }
        }
    }

    if (!diag) {
        #pragma unroll
        for (int g = 0; g < 8; g++) {
            cd[g] += __shfl_xor(cd[g], 16, 64);
            cd[g] += __shfl_xor(cd[g], 32, 64);
            ct[g] += __shfl_xor(ct[g], 16, 64);
            ct[g] += __shfl_xor(ct[g], 32, 64);
        }
        // colDT aliases Abuf[0]: last reads of Abuf[0] were chunk 4 (4&3==0),
        // retired before BAR(5); all DMA drained by vmcnt(0) at c==7; per-wave
        // writes here precede the __syncthreads below.
        if (rg == 0) {
            #pragma unroll
            for (int g = 0; g < 8; g++) {
                const int col = g * 16 + cl;
                colDT[(w * BN + col) * 2 + 0] = cd[g];
                colDT[(w * BN + col) * 2 + 1] = ct[g];
            }
        }
    }

    __syncthreads();
    if (tid >= 128 && !diag) {
        const int col = tid - 128;
        float2 v;
        v.x = colDT[(0 * BN + col) * 2 + 0] + colDT[(1 * BN + col) * 2 + 0]
            + colDT[(2 * BN + col) * 2 + 0] + colDT[(3 * BN + col) * 2 + 0];
        v.y = colDT[(0 * BN + col) * 2 + 1] + colDT[(1 * BN + col) * 2 + 1]
            + colDT[(2 * BN + col) * 2 + 1] + colDT[(3 * BN + col) * 2 + 1];
        part2[(size_t)It * BSZ + J0 + col] = v;
    }
}

// ---------------- wide per-row combine + grid-wide final (done-counter) ----------------
// 256 blocks; 8 threads per row, 8 slabs each; counter target 255.
__global__ __launch_bounds__(256) void reduce_final_kernel(
    const float* __restrict__ part, const float* __restrict__ posAcc,
    double* __restrict__ partial, unsigned int* __restrict__ counter,
    float* __restrict__ out)
{
    const int t   = threadIdx.x;
    const int row = blockIdx.x * 32 + (t >> 3);
    const int sg  = t & 7;
    float dsum = 0.f, T2 = 0.f;
    const float2* p2 = (const float2*)part;
    #pragma unroll
    for (int j = 0; j < 8; j++) {
        const float2 v = p2[(size_t)(sg * 8 + j) * BSZ + row];
        dsum += v.x; T2 += v.y;
    }
    #pragma unroll
    for (int off = 1; off < 8; off <<= 1) {
        dsum += __shfl_xor(dsum, off, 64);
        T2   += __shfl_xor(T2,   off, 64);
    }
    __shared__ double sp[32], sn[32];
    if (sg == 0) {
        const float4 pa = ((const float4*)posAcc)[row];   // {s1, w1, s2corr, cnt}
        const float s1 = pa.x, w1 = pa.y, s2 = T2 - pa.z, cnt = pa.w;
        const float pc = fmaxf(cnt, 1.0f);
        const float nc = fmaxf(8191.0f - cnt, 1.0f);
        const float ld = logf(dsum);
        sp[t >> 3] = (double)((s1 - ld * w1) / pc);
        sn[t >> 3] = (double)((s2 / dsum) / nc);
    }
    __syncthreads();
    __shared__ bool amLast;
    if (t < 32) {
        double p = sp[t], n = sn[t];
        #pragma unroll
        for (int off = 1; off < 32; off <<= 1) {
            p += __shfl_xor(p, off, 64);
            n += __shfl_xor(n, off, 64);
        }
        if (t == 0) {
            partial[blockIdx.x * 2 + 0] = p;
            partial[blockIdx.x * 2 + 1] = n;
            __threadfence();
            amLast = (atomicAdd(counter, 1u) == 255u);
        }
    }
    __syncthreads();
    if (amLast) {
        __threadfence();
        __shared__ double fp[256], fn[256];
        volatile double* vp = (volatile double*)partial;
        fp[t] = vp[t * 2 + 0];
        fn[t] = vp[t * 2 + 1];
        __syncthreads();
        for (int s = 128; s > 0; s >>= 1) {
            if (t < s) { fp[t] += fp[t + s]; fn[t] += fn[t + s]; }
            __syncthreads();
        }
        if (t == 0) out[0] = (float)(-fp[0] / (double)BSZ + 0.3 * (fn[0] / (double)BSZ));
    }
}

extern "C" void kernel_launch(void* const* d_in, const int* in_sizes, int n_in,
                              void* d_out, int out_size, void* d_ws, size_t ws_size,
                              hipStream_t stream) {
    const float* feat = (const float*)d_in[0];
    const int* labels = (const int*)d_in[1];
    float* out = (float*)d_out;

    char* ws = (char*)d_ws;
    unsigned short* anchorT = (unsigned short*)ws;                       // 4 MB MFMA-native
    const size_t anchorBytes = (size_t)BSZ * DDIM * sizeof(unsigned short);
    float* part = (float*)(ws + anchorBytes);                            // 64*8192 float2 = 4 MB
    const size_t partBytes = (size_t)NT * BSZ * 2 * sizeof(float);
    float* posAcc = (float*)(ws + anchorBytes + partBytes);              // 128 KB
    const size_t posBytes = (size_t)BSZ * 4 * sizeof(float);
    double* partial = (double*)(ws + anchorBytes + partBytes + posBytes); // 4 KB
    unsigned int* counter = (unsigned int*)(ws + anchorBytes + partBytes + posBytes + 4096);

    norm_kernel<<<BSZ / 16, 256, 0, stream>>>(feat, anchorT, posAcc, counter);
    simloss_kernel<<<NTRI, 256, 0, stream>>>(anchorT, labels, part, posAcc);
    reduce_final_kernel<<<BSZ / 32, 256, 0, stream>>>(part, posAcc, partial, counter, out);
}

// Round 12
// 108.240 us; speedup vs baseline: 1.0897x; 1.0897x over previous
//
#include <hip/hip_runtime.h>

#define BSZ  8192
#define DDIM 256
#define BM 128
#define BN 128
#define NT   64                  // tiles per dimension
#define NTRI (NT * (NT + 1) / 2) // 2080 upper-triangle tiles

typedef float f32x4 __attribute__((ext_vector_type(4)));
typedef short bf16x8 __attribute__((ext_vector_type(8)));

__device__ __forceinline__ unsigned short f32_to_bf16(float f) {
    unsigned int u = __float_as_uint(f);
    u += 0x7fffu + ((u >> 16) & 1u);   // RNE
    return (unsigned short)(u >> 16);
}

#if __has_builtin(__builtin_amdgcn_exp2f)
__device__ __forceinline__ float fast_exp2(float x) { return __builtin_amdgcn_exp2f(x); }
#else
__device__ __forceinline__ float fast_exp2(float x) {
    float r;
    asm("v_exp_f32 %0, %1" : "=v"(r) : "v"(x));
    return r;
}
#endif

// epilogue constants
#define K_E1   20.60992915555662f    // (1/T)*log2(e)
#define K_E2  -20.60992915555662f
#define K_INVT 14.285714285714286f   // 1/T
#define K_N1   1.4285714285714286f   // 1/(1-0.3)
#define K_N2   0.5714285714285714f   // 0.4/0.7

// ---------------- DPP 16-lane sum (VALU pipe, not DS pipe) ----------------
template<int CTRL>
__device__ __forceinline__ float dpp_add(float v) {
    int t = __builtin_amdgcn_update_dpp(0, __float_as_int(v), CTRL, 0xF, 0xF, true);
    return v + __int_as_float(t);
}
__device__ __forceinline__ float red16(float v) {
    v = dpp_add<0xB1>(v);    // quad_perm [1,0,3,2]  (^1)
    v = dpp_add<0x4E>(v);    // quad_perm [2,3,0,1]  (^2)
    v = dpp_add<0x141>(v);   // row_half_mirror
    v = dpp_add<0x140>(v);   // row_mirror
    return v;
}

// ---------------- LDS bank swizzle for norm staging (bijective) ----------------
__device__ __forceinline__ int swz(int b) {
    return b ^ ((((b >> 7) ^ (b >> 10)) & 7) << 4);
}

// ---------------- triangular tile decode (supertile-swizzled, 64x64) ----------------
__device__ __forceinline__ void decode_tile(int t, int& It, int& Jt) {
    const int off1 = 136, off2 = 392, off3 = 648, off4 = 904, off5 = 1040,
              off6 = 1296, off7 = 1552, off8 = 1688, off9 = 1944;
    int b = (t >= off1) + (t >= off2) + (t >= off3) + (t >= off4) + (t >= off5)
          + (t >= off6) + (t >= off7) + (t >= off8) + (t >= off9);
    int si, sj, r0;
    switch (b) {
        case 0: si = 0; sj = 0; r0 = 0;    break;
        case 1: si = 0; sj = 1; r0 = off1; break;
        case 2: si = 0; sj = 2; r0 = off2; break;
        case 3: si = 0; sj = 3; r0 = off3; break;
        case 4: si = 1; sj = 1; r0 = off4; break;
        case 5: si = 1; sj = 2; r0 = off5; break;
        case 6: si = 1; sj = 3; r0 = off6; break;
        case 7: si = 2; sj = 2; r0 = off7; break;
        case 8: si = 2; sj = 3; r0 = off8; break;
        default: si = 3; sj = 3; r0 = off9; break;
    }
    const int rr = t - r0;
    int il, jl;
    if (si == sj) {
        il = 0;
        #pragma unroll
        for (int q = 1; q < 16; q++) if (rr >= (16 * q - (q * (q - 1)) / 2)) il = q;
        jl = il + (rr - (16 * il - (il * (il - 1)) / 2));
    } else {
        il = rr >> 4;
        jl = rr & 15;
    }
    It = si * 16 + il;
    Jt = sj * 16 + jl;
}

// ---------------- L2-normalize rows; MFMA-native output; zero posAcc+counter ----------------
__global__ __launch_bounds__(256) void norm_kernel(const float* __restrict__ feat,
                                                   unsigned short* __restrict__ anchorT,
                                                   float* __restrict__ posAcc,
                                                   unsigned int* __restrict__ counter) {
    __shared__ __align__(16) unsigned short img[8 * 512];    // 8 KB: 8 x 1KB tiles
    char* const imgb = (char*)img;
    const int tid  = threadIdx.x;
    const int wid  = tid >> 6;
    const int lane = tid & 63;
    const int R    = blockIdx.x;          // 16-row tile
    const int R0   = R * 16;

    if (tid < 64) posAcc[blockIdx.x * 64 + tid] = 0.0f;       // 512*64 = 32768 = BSZ*4
    if (blockIdx.x == 0 && tid == 0) *counter = 0u;

    #pragma unroll
    for (int it = 0; it < 4; it++) {
        const int row = R0 + it * 4 + wid;
        const float4 v = ((const float4*)(feat + (size_t)row * DDIM))[lane];
        float ss = v.x * v.x + v.y * v.y + v.z * v.z + v.w * v.w;
        #pragma unroll
        for (int off = 32; off > 0; off >>= 1) ss += __shfl_xor(ss, off, 64);
        const float inv = rsqrtf(ss);
        ushort4 o;
        o.x = f32_to_bf16(v.x * inv);
        o.y = f32_to_bf16(v.y * inv);
        o.z = f32_to_bf16(v.z * inv);
        o.w = f32_to_bf16(v.w * inv);
        const int C    = lane >> 3;                           // k/32 (k = lane*4)
        const int l16  = (row & 15) + (((lane >> 1) & 3) << 4);
        const int wb   = (C << 10) + (l16 << 4) + ((lane & 1) << 3);
        *(ushort4*)(imgb + swz(wb)) = o;
    }
    __syncthreads();
    #pragma unroll
    for (int p = 0; p < 2; p++) {
        const int c = p * 4 + wid;                            // chunk 0..7 (= C)
        *(bf16x8*)(anchorT + ((size_t)(c * 512 + R)) * 512 + lane * 8) =
            *(const bf16x8*)(imgb + swz((c << 10) + (lane << 4)));
    }
}

// ---------------- async global -> LDS, 16B/lane ----------------
__device__ __forceinline__ void gload_lds16(const unsigned short* g, unsigned short* l) {
    __builtin_amdgcn_global_load_lds(
        (const __attribute__((address_space(1))) void*)g,
        (__attribute__((address_space(3))) void*)l, 16, 0, 0);
}

// ---------------- fused 128x128 sim-tile + loss partials (upper triangle) ----------------
// 256 threads / 4 waves; wave = 32x128 sub-tile (2 A-frag x 8 B-frag, acc[2][8]).
// TRIPLE-buffered LDS (3 x 8 KB for A, 3 x 8 KB for B = 48 KB): writer of
// iteration c targets buf[(c+1)%3]; the earliest rewrite of buf[c%3] is at
// iteration c+2 (stages (c+3)%3 == c%3), and every wave's reads of c%3 retired
// before BAR(c+1) (compiler lgkmcnt precedes MFMA operand use). -> ONE barrier
// per chunk (8 total) and NO explicit lgkmcnt drain. Counted vmcnt(4) keeps
// chunk c+1's 4 DMA loads in flight across the barrier. s_setprio(1) wraps the
// MFMA cluster (3 independent blocks/CU = role diversity, T5 regime).
// FINAL-CONFIG LEDGER (all measured):
//   256^2 tile spills (R5/R6, 34-97 MB scratch); tight reg caps spill (R3);
//   A-bypass-LDS -2.4us (R9); 4-buf depth-2 prefetch -9us via 2 blocks/CU
//   occupancy loss (R11); needW epilogue fast-path null (R4).
//   This (R8) configuration = best measured: 108.4 / 108.8 us total.
__global__ __launch_bounds__(256, 3) void simloss_kernel(
    const unsigned short* __restrict__ anchorT,
    const int* __restrict__ labels,
    float* __restrict__ part,          // float2 [NT][BSZ]
    float* __restrict__ posAcc)        // [BSZ][4] {s1, w1, s2corr, cnt}
{
    __shared__ __align__(16) unsigned short Abuf[3][4096];   // 3 x 8 KB
    __shared__ __align__(16) unsigned short Bbuf[3][4096];   // 3 x 8 KB
    float* const colDT = (float*)Abuf;   // [4][128][2] = 4 KB alias (epilogue only)

    int It, Jt;
    decode_tile(blockIdx.x, It, Jt);
    const bool diag = (It == Jt);
    const int I0 = It * BM, J0 = Jt * BN;

    const int tid  = threadIdx.x;
    const int lane = tid & 63;
    const int w    = tid >> 6;       // 0..3 ; wave rows w*32..+31
    const int cl   = lane & 15;
    const int rg   = lane >> 4;
    const int laneOff = lane * 8;    // shorts (16 B)

    f32x4 acc[2][8];
    #pragma unroll
    for (int f = 0; f < 2; f++)
        #pragma unroll
        for (int g = 0; g < 8; g++)
            acc[f][g] = (f32x4){0.f, 0.f, 0.f, 0.f};

    // chunk c = 32-wide K slice; anchorT granule layout [c][512 rowtiles][512]
    const unsigned short* aSrc = anchorT + (size_t)It * 4096;
    const unsigned short* bSrc = anchorT + (size_t)Jt * 4096;

    // 4 gloads/thread/chunk: each wave stages 2 of the 8 granules per matrix
    #define STAGE(c, b)                                                                 \
        do {                                                                            \
            const size_t off = (size_t)(c) * 262144;                                    \
            gload_lds16(aSrc + off + tid * 8,        &Abuf[b][w * 512]);                \
            gload_lds16(aSrc + off + 2048 + tid * 8, &Abuf[b][2048 + w * 512]);         \
            gload_lds16(bSrc + off + tid * 8,        &Bbuf[b][w * 512]);                \
            gload_lds16(bSrc + off + 2048 + tid * 8, &Bbuf[b][2048 + w * 512]);         \
        } while (0)

    STAGE(0, 0);

    #pragma unroll
    for (int c = 0; c < 8; c++) {
        if (c < 7) {
            STAGE(c + 1, (c + 1) % 3);
            asm volatile("s_waitcnt vmcnt(4)" ::: "memory");   // chunk c landed; c+1 in flight
        } else {
            asm volatile("s_waitcnt vmcnt(0)" ::: "memory");
        }
        __builtin_amdgcn_s_barrier();
        __builtin_amdgcn_sched_barrier(0);   // keep ds_reads below the barrier

        const int bc = c % 3;
        const unsigned short* aB = &Abuf[bc][(w * 2) * 512 + laneOff];
        const unsigned short* bB = &Bbuf[bc][laneOff];
        const bf16x8 a0 = *(const bf16x8*)(aB);
        const bf16x8 a1 = *(const bf16x8*)(aB + 512);
        __builtin_amdgcn_s_setprio(1);
        #pragma unroll
        for (int gh = 0; gh < 2; gh++) {
            const bf16x8 b0 = *(const bf16x8*)(bB + (gh * 4 + 0) * 512);
            const bf16x8 b1 = *(const bf16x8*)(bB + (gh * 4 + 1) * 512);
            const bf16x8 b2 = *(const bf16x8*)(bB + (gh * 4 + 2) * 512);
            const bf16x8 b3 = *(const bf16x8*)(bB + (gh * 4 + 3) * 512);
            acc[0][gh*4+0] = __builtin_amdgcn_mfma_f32_16x16x32_bf16(a0, b0, acc[0][gh*4+0], 0, 0, 0);
            acc[1][gh*4+0] = __builtin_amdgcn_mfma_f32_16x16x32_bf16(a1, b0, acc[1][gh*4+0], 0, 0, 0);
            acc[0][gh*4+1] = __builtin_amdgcn_mfma_f32_16x16x32_bf16(a0, b1, acc[0][gh*4+1], 0, 0, 0);
            acc[1][gh*4+1] = __builtin_amdgcn_mfma_f32_16x16x32_bf16(a1, b1, acc[1][gh*4+1], 0, 0, 0);
            acc[0][gh*4+2] = __builtin_amdgcn_mfma_f32_16x16x32_bf16(a0, b2, acc[0][gh*4+2], 0, 0, 0);
            acc[1][gh*4+2] = __builtin_amdgcn_mfma_f32_16x16x32_bf16(a1, b2, acc[1][gh*4+2], 0, 0, 0);
            acc[0][gh*4+3] = __builtin_amdgcn_mfma_f32_16x16x32_bf16(a0, b3, acc[0][gh*4+3], 0, 0, 0);
            acc[1][gh*4+3] = __builtin_amdgcn_mfma_f32_16x16x32_bf16(a1, b3, acc[1][gh*4+3], 0, 0, 0);
        }
        __builtin_amdgcn_s_setprio(0);
        // no trailing barrier: buf[c%3] is not rewritten until iteration c+2,
        // and all reads of it retired before BAR(c+1).
    }
    #undef STAGE

    // ---- epilogue: single pass; rows stored direct; labels from global (L2-hot) ----
    int lj[8];
    #pragma unroll
    for (int g = 0; g < 8; g++) lj[g] = labels[J0 + g * 16 + cl];

    float cd[8] = {0.f,0.f,0.f,0.f,0.f,0.f,0.f,0.f};
    float ct[8] = {0.f,0.f,0.f,0.f,0.f,0.f,0.f,0.f};
    float2* const part2 = (float2*)part;

    #pragma unroll
    for (int f = 0; f < 2; f++) {
        float rd[4] = {0.f, 0.f, 0.f, 0.f}, rt[4] = {0.f, 0.f, 0.f, 0.f};
        const int rbase = I0 + w * 32 + f * 16 + rg * 4;
        const int4 lv = *(const int4*)(labels + rbase);
        const int li[4] = {lv.x, lv.y, lv.z, lv.w};
        #pragma unroll
        for (int g = 0; g < 8; g++) {
            const int lj_ = lj[g];
            const bool granule = (w * 2 + f) == g;   // 16x16 block on tile diagonal
            const f32x4 c4 = acc[f][g];
            #pragma unroll
            for (int r = 0; r < 4; r++) {
                const float s = c4[r];
                const bool self = diag && granule && ((rg * 4 + r) == cl);
                const float e  = self ? 0.f : fast_exp2(fmaf(s, K_E1, K_E2));
                const float wn = fmaxf(fmaf(s, K_N1, K_N2), 1.0f);
                const float we = wn * e;
                rd[r] += e;  rt[r] += we;
                if (!diag) { cd[g] += e; ct[g] += we; }
                if (li[r] == lj_ && !self) {   // rare (~0.1%)
                    const float wp = fmaxf(1.5f - s, 1.0f);
                    const float slp = fmaf(s, K_INVT, -K_INVT) * wp;
                    float* pi = posAcc + (size_t)(rbase + r) * 4;
                    atomicAdd(pi + 0, slp);
                    atomicAdd(pi + 1, wp);
                    atomicAdd(pi + 2, we);
                    atomicAdd(pi + 3, 1.0f);
                    if (!diag) {
                        float* pj = posAcc + (size_t)(J0 + g * 16 + cl) * 4;
                        atomicAdd(pj + 0, slp);
                        atomicAdd(pj + 1, wp);
                        atomicAdd(pj + 2, we);
                        atomicAdd(pj + 3, 1.0f);
                    }
                }
            }
        }
        #pragma unroll
        for (int r = 0; r < 4; r++) {
            rd[r] = red16(rd[r]);
            rt[r] = red16(rt[r]);
        }
        if (cl == 0) {
            #pragma unroll
            for (int r = 0; r < 4; r++) {
                float2 v; v.x = rd[r]; v.y = rt[r];
                part2[(size_t)Jt * BSZ + rbase + r] = v;   // rows are wave-local
            }
        }
    }

    if (!diag) {
        #pragma unroll
        for (int g = 0; g < 8; g++) {
            cd[g] += __shfl_xor(cd[g], 16, 64);
            cd[g] += __shfl_xor(cd[g], 32, 64);
            ct[g] += __shfl_xor(ct[g], 16, 64);
            ct[g] += __shfl_xor(ct[g], 32, 64);
        }
        // colDT aliases Abuf[0]: safe -- last read of Abuf[0] was chunk 6
        // (6%3==0), all waves passed BAR(7) since, and per-wave writes here
        // precede the __syncthreads below.
        if (rg == 0) {
            #pragma unroll
            for (int g = 0; g < 8; g++) {
                const int col = g * 16 + cl;
                colDT[(w * BN + col) * 2 + 0] = cd[g];
                colDT[(w * BN + col) * 2 + 1] = ct[g];
            }
        }
    }

    __syncthreads();
    if (tid >= 128 && !diag) {
        const int col = tid - 128;
        float2 v;
        v.x = colDT[(0 * BN + col) * 2 + 0] + colDT[(1 * BN + col) * 2 + 0]
            + colDT[(2 * BN + col) * 2 + 0] + colDT[(3 * BN + col) * 2 + 0];
        v.y = colDT[(0 * BN + col) * 2 + 1] + colDT[(1 * BN + col) * 2 + 1]
            + colDT[(2 * BN + col) * 2 + 1] + colDT[(3 * BN + col) * 2 + 1];
        part2[(size_t)It * BSZ + J0 + col] = v;
    }
}

// ---------------- wide per-row combine + grid-wide final (done-counter) ----------------
// 256 blocks; 8 threads per row, 8 slabs each; counter target 255.
__global__ __launch_bounds__(256) void reduce_final_kernel(
    const float* __restrict__ part, const float* __restrict__ posAcc,
    double* __restrict__ partial, unsigned int* __restrict__ counter,
    float* __restrict__ out)
{
    const int t   = threadIdx.x;
    const int row = blockIdx.x * 32 + (t >> 3);
    const int sg  = t & 7;
    float dsum = 0.f, T2 = 0.f;
    const float2* p2 = (const float2*)part;
    #pragma unroll
    for (int j = 0; j < 8; j++) {
        const float2 v = p2[(size_t)(sg * 8 + j) * BSZ + row];
        dsum += v.x; T2 += v.y;
    }
    #pragma unroll
    for (int off = 1; off < 8; off <<= 1) {
        dsum += __shfl_xor(dsum, off, 64);
        T2   += __shfl_xor(T2,   off, 64);
    }
    __shared__ double sp[32], sn[32];
    if (sg == 0) {
        const float4 pa = ((const float4*)posAcc)[row];   // {s1, w1, s2corr, cnt}
        const float s1 = pa.x, w1 = pa.y, s2 = T2 - pa.z, cnt = pa.w;
        const float pc = fmaxf(cnt, 1.0f);
        const float nc = fmaxf(8191.0f - cnt, 1.0f);
        const float ld = logf(dsum);
        sp[t >> 3] = (double)((s1 - ld * w1) / pc);
        sn[t >> 3] = (double)((s2 / dsum) / nc);
    }
    __syncthreads();
    __shared__ bool amLast;
    if (t < 32) {
        double p = sp[t], n = sn[t];
        #pragma unroll
        for (int off = 1; off < 32; off <<= 1) {
            p += __shfl_xor(p, off, 64);
            n += __shfl_xor(n, off, 64);
        }
        if (t == 0) {
            partial[blockIdx.x * 2 + 0] = p;
            partial[blockIdx.x * 2 + 1] = n;
            __threadfence();
            amLast = (atomicAdd(counter, 1u) == 255u);
        }
    }
    __syncthreads();
    if (amLast) {
        __threadfence();
        __shared__ double fp[256], fn[256];
        volatile double* vp = (volatile double*)partial;
        fp[t] = vp[t * 2 + 0];
        fn[t] = vp[t * 2 + 1];
        __syncthreads();
        for (int s = 128; s > 0; s >>= 1) {
            if (t < s) { fp[t] += fp[t + s]; fn[t] += fn[t + s]; }
            __syncthreads();
        }
        if (t == 0) out[0] = (float)(-fp[0] / (double)BSZ + 0.3 * (fn[0] / (double)BSZ));
    }
}

extern "C" void kernel_launch(void* const* d_in, const int* in_sizes, int n_in,
                              void* d_out, int out_size, void* d_ws, size_t ws_size,
                              hipStream_t stream) {
    const float* feat = (const float*)d_in[0];
    const int* labels = (const int*)d_in[1];
    float* out = (float*)d_out;

    char* ws = (char*)d_ws;
    unsigned short* anchorT = (unsigned short*)ws;                       // 4 MB MFMA-native
    const size_t anchorBytes = (size_t)BSZ * DDIM * sizeof(unsigned short);
    float* part = (float*)(ws + anchorBytes);                            // 64*8192 float2 = 4 MB
    const size_t partBytes = (size_t)NT * BSZ * 2 * sizeof(float);
    float* posAcc = (float*)(ws + anchorBytes + partBytes);              // 128 KB
    const size_t posBytes = (size_t)BSZ * 4 * sizeof(float);
    double* partial = (double*)(ws + anchorBytes + partBytes + posBytes); // 4 KB
    unsigned int* counter = (unsigned int*)(ws + anchorBytes + partBytes + posBytes + 4096);

    norm_kernel<<<BSZ / 16, 256, 0, stream>>>(feat, anchorT, posAcc, counter);
    simloss_kernel<<<NTRI, 256, 0, stream>>>(anchorT, labels, part, posAcc);
    reduce_final_kernel<<<BSZ / 32, 256, 0, stream>>>(part, posAcc, partial, counter, out);
}